// Round 14
// baseline (294.675 us; speedup 1.0000x reference)
//
#include <hip/hip_runtime.h>

#define N_NODES 512
#define C_CH    128
#define S_SPEC  10
#define KT      50
#define NT      11

typedef _Float16 h8 __attribute__((ext_vector_type(8)));
typedef float f32x4 __attribute__((ext_vector_type(4)));

// K layout: 50 tiles x 32 slots; tile = 4 octets (one per lane-group g).
// Octet = (offA, offB, j0): slot i computes x[offA]*x[offB]*x[j0+i], j0 in {0,8}.
// N cols (o-major): nt 0..6 = k3, 7..9 = k2, 10 = k1; col = o (0..15).
__device__ h8 g_Bf[KT * NT * 64];   // B pre-swizzled to MFMA B-frag order [kt][nt][lane]
__device__ h8 g_Wf[128 * 64];       // wlin as A-frags: [mt*16+ks][lane], K-expanded (ir,cc)

__device__ __forceinline__ int fc_of(int kt)  { return kt < 43 ? 7 : (kt < 49 ? 3 : 1); }
__device__ __forceinline__ int ntb_of(int kt) { return kt < 43 ? 0 : (kt < 49 ? 7 : 10); }

__device__ __forceinline__ void o_to_iri(int o, int& ir, int& i) {
  if (o >= 9)      { ir = 3; i = o - 9; }
  else if (o >= 4) { ir = 2; i = o - 4; }
  else if (o >= 1) { ir = 1; i = o - 1; }
  else             { ir = 0; i = 0; }
}

__device__ int octet_desc(int Q) {
  if (Q < 172) {                     // order-3
    int q = Q;
    for (int a = 0; a < 16; ++a)
      for (int b = a; b < 16; ++b) {
        int no = (b < 8) ? 2 : 1;
        if (q < no) {
          int jb = (no == 1) ? 1 : q;          // b<8: q0->j0=0,q1->j0=8; b>=8: j0=8
          return a | (b << 5) | (jb << 10);
        }
        q -= no;
      }
  } else if (Q < 196) {              // order-2
    int q = Q - 172;
    for (int a = 0; a < 16; ++a) {
      int no = (a < 8) ? 2 : 1;
      if (q < no) {
        int jb = (no == 1) ? 1 : q;
        return a | (16 << 5) | (jb << 10);
      }
      q -= no;
    }
  } else if (Q < 198) {              // order-1
    return 16 | (16 << 5) | ((Q - 196) << 10);
  }
  return 17 | (17 << 5);             // pad (zero column)
}

// ---- merged build: virtual bids 0..319 build B fragments, 320..447 build W fragments ----
__global__ void build_all(const float* __restrict__ u1_0, const float* __restrict__ u1_1,
                          const float* __restrict__ u1_2, const float* __restrict__ u1_3,
                          const float* __restrict__ u2_0, const float* __restrict__ u2_1,
                          const float* __restrict__ u2_2, const float* __restrict__ u2_3,
                          const float* __restrict__ u3_0, const float* __restrict__ u3_1,
                          const float* __restrict__ u3_2, const float* __restrict__ u3_3,
                          const float* __restrict__ wlin) {
  const int id  = blockIdx.x * 256 + threadIdx.x;   // 112*256 = 448*64
  const int bid = id >> 6;
  const int l   = id & 63;
  const int dis[4] = {1, 3, 5, 7};
  if (bid < 320) {
    int kt, nt;
    if (bid < 301)      { kt = bid / 7; nt = bid % 7; }
    else if (bid < 319) { int e = bid - 301; kt = 43 + e / 3; nt = 7 + e % 3; }
    else                { kt = 49; nt = 10; }

    const int o = l & 15;
    int ir, ii; o_to_iri(o, ir, ii);
    const int di = dis[ir];
    const float* u1s[4] = {u1_0, u1_1, u1_2, u1_3};
    const float* u2s[4] = {u2_0, u2_1, u2_2, u2_3};
    const float* u3s[4] = {u3_0, u3_1, u3_2, u3_3};

    const int rt = octet_desc(kt * 4 + (l >> 4));
    const int oA = rt & 31, oB = (rt >> 5) & 31, j0 = ((rt >> 10) & 1) * 8;

    h8 v;
#pragma unroll
    for (int i = 0; i < 8; ++i) {
      const int j = j0 + i;
      float val = 0.f;
      if (oA < 16 && oB < 16) {              // order-3, canonical a<=b<=j
        if (j >= oB) {
          const float* u = u3s[ir];
          int a = oA, b = oB;
          int P[6][3] = {{a,b,j},{a,j,b},{b,a,j},{b,j,a},{j,a,b},{j,b,a}};
          for (int p = 0; p < 6; ++p) {
            bool dup = false;
            for (int r = 0; r < p; ++r)
              if (P[r][0] == P[p][0] && P[r][1] == P[p][1] && P[r][2] == P[p][2]) { dup = true; break; }
            if (!dup)
              val += u[(((P[p][0] * 16 + P[p][1]) * 16 + P[p][2]) * 7 + nt) * di + ii];
          }
        }
      } else if (oA < 16 && oB == 16) {      // order-2 (oA <= j)
        if (j >= oA) {
          const int k2 = nt - 7;
          const float* u = u2s[ir];
          val = u[((oA * 16 + j) * 3 + k2) * di + ii];
          if (j != oA) val += u[((j * 16 + oA) * 3 + k2) * di + ii];
        }
      } else if (oA == 16) {                 // order-1
        val = u1s[ir][j * di + ii];
      }
      v[i] = (_Float16)val;
    }
    g_Bf[((size_t)kt * NT + nt) * 64 + l] = v;
  } else {
    // wlin -> fp16 A-frags over expanded K = (ir*128+cc), scaled by 1/sqrt(128)
    const int idW = (bid - 320) * 64 + l;    // 8192 total
    const int ks = (idW >> 6) & 15, mt = idW >> 10;
    const int f = mt * 16 + (l & 15);
    const float inv = 0.08838834764831845f;
    h8 v;
#pragma unroll
    for (int i = 0; i < 8; ++i) {
      const int k = ks * 32 + (l >> 4) * 8 + i;
      const int ir = k >> 7, cc = k & 127;
      v[i] = (_Float16)(wlin[((size_t)ir * C_CH + cc) * C_CH + f] * inv);
    }
    g_Wf[(mt * 16 + ks) * 64 + l] = v;
  }
}

// ---------------- fused main kernel: 1024 thr, in-block K-split (even/odd tiles) ----------------
// waves 0-7: even kt; waves 8-15: odd kt. 2 nodes/block, grid 256 = 1 block/CU.
// NOTE: 1024 threads hard-caps VGPR at 128; main loop measured 92 (R11). No min-waves arg.
// LDS: bsA+bsB 112K + xT 18.4K + rtab 0.8K = 134K. red0/red1 alias bsB, Ef aliases bsA.

#define MFMA16(A, B, C) __builtin_amdgcn_mfma_f32_16x16x32_f16(A, B, C, 0, 0, 0)

__global__ __launch_bounds__(1024, 1) void eqp_mm(
    const float* __restrict__ x, const int* __restrict__ specie,
    const float* __restrict__ w1, const float* __restrict__ w2,
    const float* __restrict__ w3, float* __restrict__ out) {
  __shared__ __align__(16) char bsA[2][28 * 1024];
  __shared__ __align__(16) char bsB[2][28 * 1024];
  __shared__ float xT[2][128][18];                  // cols 0..15 x, 16 = 1, 17 = 0
  __shared__ int rtab[KT * 4];

  const int t = threadIdx.x;
  const int l = t & 63;
  const int w = t >> 6;          // 0..15
  const int h = w >> 3;          // K-half: 0 -> even kt, 1 -> odd kt
  const int wv = w & 7;          // wave within half
  const int g = l >> 4;
  const int n0 = blockIdx.x * 2;

  if (t < 512) {  // stage xT (R10 pattern, low-conflict)
    const int p = t >> 8, c = (t >> 1) & 127, half = t & 1;
    const float* xp = x + ((size_t)(n0 + p) * C_CH + c) * 16 + half * 8;
    const float4 v0 = *(const float4*)xp, v1 = *(const float4*)(xp + 4);
    float* row = &xT[p][c][half * 8];
    row[0] = v0.x; row[1] = v0.y; row[2] = v0.z; row[3] = v0.w;
    row[4] = v1.x; row[5] = v1.y; row[6] = v1.z; row[7] = v1.w;
    if (half == 1) { xT[p][c][16] = 1.f; xT[p][c][17] = 0.f; }
  }
  if (t < KT * 4) rtab[t] = octet_desc(t);

  const int ch = wv * 16 + (l & 15);
  const int s0 = specie[n0], s1 = specie[n0 + 1];

  // packed fp16 x registers (RTE) for pk-mul A production
  auto packh = [](float4 u, float4 v) {
    h8 r;
    r[0] = (_Float16)u.x; r[1] = (_Float16)u.y; r[2] = (_Float16)u.z; r[3] = (_Float16)u.w;
    r[4] = (_Float16)v.x; r[5] = (_Float16)v.y; r[6] = (_Float16)v.z; r[7] = (_Float16)v.w;
    return r;
  };
  h8 xh[2][2];
  {
    const float4* p0 = (const float4*)(x + ((size_t)n0 * C_CH + ch) * 16);
    xh[0][0] = packh(p0[0], p0[1]); xh[0][1] = packh(p0[2], p0[3]);
    const float4* p1 = (const float4*)(x + ((size_t)(n0 + 1) * C_CH + ch) * 16);
    xh[1][0] = packh(p1[0], p1[1]); xh[1][1] = packh(p1[2], p1[3]);
  }

  f32x4 acc[2][NT];
#pragma unroll
  for (int p = 0; p < 2; ++p)
#pragma unroll
    for (int i = 0; i < NT; ++i) acc[p][i] = (f32x4){0.f, 0.f, 0.f, 0.f};

  char (*bs)[28 * 1024] = h ? bsB : bsA;

  h8 tv[4]; int dst[4];

  // half h's tile i (0..24) is kt = h + 2*i; chunks of 4 tiles
  auto issue = [&](int ck) {
    const int i0 = ck * 4;
    int cnt[4];
#pragma unroll
    for (int tt = 0; tt < 4; ++tt) {
      const int i = i0 + tt;
      cnt[tt] = (i < 25) ? fc_of(h + 2 * i) : 0;
    }
#pragma unroll
    for (int s2 = 0; s2 < 4; ++s2) {
      const int fi = s2 * 8 + wv;
      int rem = fi, tt = 0;
      while (tt < 4 && rem >= cnt[tt]) { rem -= cnt[tt]; ++tt; }
      const bool ok = tt < 4;
      dst[s2] = ok ? fi : -1;
      if (ok) {
        const int kt = h + 2 * (i0 + tt);
        const int nt = ntb_of(kt) + rem;
        tv[s2] = g_Bf[((size_t)kt * NT + nt) * 64 + l];
      }
    }
  };
  auto wr = [&](char* buf) {
#pragma unroll
    for (int s2 = 0; s2 < 4; ++s2)
      if (dst[s2] >= 0) *(h8*)&buf[(size_t)dst[s2] * 1024 + (size_t)l * 16] = tv[s2];
  };

#define BRD(i) (*(const h8*)&buf[(size_t)(fb2 + (i)) * 1024 + (size_t)l * 16])

  auto consume = [&](int ck, const char* buf) {
    const int i0 = ck * 4;
    int fb2 = 0;
#pragma unroll
    for (int tt = 0; tt < 4; ++tt) {
      const int i = i0 + tt;
      if (i >= 25) continue;
      const int kt = h + 2 * i;
      const int rt_ = rtab[kt * 4 + g];
      const int oA_ = rt_ & 31, oB_ = (rt_ >> 5) & 31, jb_ = (rt_ >> 10) & 1;
      const float xab0 = xT[0][ch][oA_] * xT[0][ch][oB_];
      const float xab1 = xT[1][ch][oA_] * xT[1][ch][oB_];
      const _Float16 hm0 = (_Float16)xab0, hm1 = (_Float16)xab1;   // RTE
      const h8 m0 = {hm0, hm0, hm0, hm0, hm0, hm0, hm0, hm0};
      const h8 m1 = {hm1, hm1, hm1, hm1, hm1, hm1, hm1, hm1};
      const h8 af0 = m0 * (jb_ ? xh[0][1] : xh[0][0]);   // v_pk_mul_f16
      const h8 af1 = m1 * (jb_ ? xh[1][1] : xh[1][0]);
      if (kt < 43) {
        h8 b0 = BRD(0), b1 = BRD(1), b2 = BRD(2), b3 = BRD(3), b4 = BRD(4), b5 = BRD(5), b6 = BRD(6);
        acc[0][0] = MFMA16(af0, b0, acc[0][0]); acc[1][0] = MFMA16(af1, b0, acc[1][0]);
        acc[0][1] = MFMA16(af0, b1, acc[0][1]); acc[1][1] = MFMA16(af1, b1, acc[1][1]);
        acc[0][2] = MFMA16(af0, b2, acc[0][2]); acc[1][2] = MFMA16(af1, b2, acc[1][2]);
        acc[0][3] = MFMA16(af0, b3, acc[0][3]); acc[1][3] = MFMA16(af1, b3, acc[1][3]);
        acc[0][4] = MFMA16(af0, b4, acc[0][4]); acc[1][4] = MFMA16(af1, b4, acc[1][4]);
        acc[0][5] = MFMA16(af0, b5, acc[0][5]); acc[1][5] = MFMA16(af1, b5, acc[1][5]);
        acc[0][6] = MFMA16(af0, b6, acc[0][6]); acc[1][6] = MFMA16(af1, b6, acc[1][6]);
        fb2 += 7;
      } else if (kt < 49) {
        h8 b0 = BRD(0), b1 = BRD(1), b2 = BRD(2);
        acc[0][7] = MFMA16(af0, b0, acc[0][7]); acc[1][7] = MFMA16(af1, b0, acc[1][7]);
        acc[0][8] = MFMA16(af0, b1, acc[0][8]); acc[1][8] = MFMA16(af1, b1, acc[1][8]);
        acc[0][9] = MFMA16(af0, b2, acc[0][9]); acc[1][9] = MFMA16(af1, b2, acc[1][9]);
        fb2 += 3;
      } else {
        h8 b0 = BRD(0);
        acc[0][10] = MFMA16(af0, b0, acc[0][10]); acc[1][10] = MFMA16(af1, b0, acc[1][10]);
        fb2 += 1;
      }
    }
  };

  // ---- pipelined main loop: 7 chunks of up-to-4 tiles per half; 1 barrier/chunk ----
  issue(0);
  __syncthreads();           // xT/rtab visible
  wr(bs[0]);
  __syncthreads();
#pragma unroll 1
  for (int ck = 0; ck < 7; ++ck) {
    if (ck < 6) issue(ck + 1);
    consume(ck, bs[ck & 1]);
    if (ck < 6) {
      wr(bs[(ck & 1) ^ 1]);   // last read a chunk ago, barrier-separated
      __syncthreads();
    }
  }

  // ---- species fold per half (register-only) ----
  const int o = l & 15;
  int ir, ii; o_to_iri(o, ir, ii); (void)ii;
  const int cb = wv * 16 + g * 4;
  f32x4 tot[2];
#pragma unroll
  for (int p = 0; p < 2; ++p) {
    const int sp = p ? s1 : s0;
    f32x4 tt2 = {0.f, 0.f, 0.f, 0.f};
#pragma unroll
    for (int k = 0; k < 7; ++k) {
      const float4 wv4 = *(const float4*)(w3 + ((size_t)(ir * S_SPEC + sp) * 7 + k) * C_CH + cb);
      tt2[0] = fmaf(wv4.x, acc[p][k][0], tt2[0]);
      tt2[1] = fmaf(wv4.y, acc[p][k][1], tt2[1]);
      tt2[2] = fmaf(wv4.z, acc[p][k][2], tt2[2]);
      tt2[3] = fmaf(wv4.w, acc[p][k][3], tt2[3]);
    }
#pragma unroll
    for (int k = 0; k < 3; ++k) {
      const float4 wv4 = *(const float4*)(w2 + ((size_t)(ir * S_SPEC + sp) * 3 + k) * C_CH + cb);
      tt2[0] = fmaf(wv4.x, acc[p][7 + k][0], tt2[0]);
      tt2[1] = fmaf(wv4.y, acc[p][7 + k][1], tt2[1]);
      tt2[2] = fmaf(wv4.z, acc[p][7 + k][2], tt2[2]);
      tt2[3] = fmaf(wv4.w, acc[p][7 + k][3], tt2[3]);
    }
    {
      const float4 wv4 = *(const float4*)(w1 + (size_t)(ir * S_SPEC + sp) * C_CH + cb);
      tt2[0] = fmaf(wv4.x, acc[p][10][0], tt2[0]);
      tt2[1] = fmaf(wv4.y, acc[p][10][1], tt2[1]);
      tt2[2] = fmaf(wv4.z, acc[p][10][2], tt2[2]);
      tt2[3] = fmaf(wv4.w, acc[p][10][3], tt2[3]);
    }
    tot[p] = tt2;
  }

  __syncthreads();   // all B-buffer reads done; safe to alias

  // ---- write per-half partials (red0/red1 alias bsB) + zero Ef (aliases bsA) ----
  float* red0 = (float*)&bsB[0][0];   // [p][o][132]
  float* red1 = (float*)&bsB[1][0];
  _Float16* Ef = (_Float16*)&bsA[0][0];  // [p][ks16][lg4][o16][i8] = 32 KB (spans bsA)
  {
    float* redH = h ? red1 : red0;
#pragma unroll
    for (int p = 0; p < 2; ++p) {
      float4 st = {tot[p][0], tot[p][1], tot[p][2], tot[p][3]};
      *(float4*)&redH[(p * 16 + o) * 132 + cb] = st;
    }
    float4* z = (float4*)Ef;
    z[t] = (float4){0.f, 0.f, 0.f, 0.f};
    z[t + 1024] = (float4){0.f, 0.f, 0.f, 0.f};
  }
  __syncthreads();

  // ---- merge halves, scatter to Ef (fp16) ----
  {
    const int off = t;                      // float4 index over [p][o][c/4]
    const int p = off >> 9, oo = (off >> 5) & 15, c4 = off & 31;
    const int base = (p * 16 + oo) * 132 + c4 * 4;
    const float4 A0 = *(const float4*)&red0[base];
    const float4 A1 = *(const float4*)&red1[base];
    float av[4] = {A0.x + A1.x, A0.y + A1.y, A0.z + A1.z, A0.w + A1.w};
    int ir2, ii2; o_to_iri(oo, ir2, ii2); (void)ii2;
#pragma unroll
    for (int r = 0; r < 4; ++r) {
      const int k = ir2 * 128 + c4 * 4 + r;
      Ef[(((p * 16 + (k >> 5)) * 4 + ((k >> 3) & 3)) * 16 + oo) * 8 + (k & 7)] = (_Float16)av[r];
    }
  }
  __syncthreads();

  // ---- wlin channel mix via MFMA: wave w -> node p=w>>3, M-tile mt=w&7 ----
  {
    const int p = h;         // w>>3
    const int mt = wv;       // w&7
    f32x4 D = {0.f, 0.f, 0.f, 0.f};
#pragma unroll
    for (int ks = 0; ks < 16; ++ks) {
      const h8 aw = g_Wf[(mt * 16 + ks) * 64 + l];
      const h8 b = *(const h8*)&Ef[(((p * 16 + ks) * 4 + (l >> 4)) * 16 + (l & 15)) * 8];
      D = MFMA16(aw, b, D);
    }
    const int dis[4]  = {1, 3, 5, 7};
    const int ooff[4] = {0, 128, 512, 1152};
    int ir2, ii2; o_to_iri(o, ir2, ii2);
    const size_t base = (size_t)(n0 + p) * 2048 + ooff[ir2] + ii2;
#pragma unroll
    for (int r = 0; r < 4; ++r) {
      const int f = mt * 16 + (l >> 4) * 4 + r;
      out[base + (size_t)f * dis[ir2]] = D[r];
    }
  }
}

// ---------------- launch ----------------

extern "C" void kernel_launch(void* const* d_in, const int* in_sizes, int n_in,
                              void* d_out, int out_size, void* d_ws, size_t ws_size,
                              hipStream_t stream) {
  const float* x      = (const float*)d_in[0];
  const int*   specie = (const int*)d_in[1];

  const float *u1s[4], *u2s[4], *u3s[4];
  if (in_sizes[3] == 768) {  // interleaved dict order: u1_0,u2_0,u3_0,u1_1,...
    for (int i = 0; i < 4; ++i) {
      u1s[i] = (const float*)d_in[2 + 3 * i];
      u2s[i] = (const float*)d_in[3 + 3 * i];
      u3s[i] = (const float*)d_in[4 + 3 * i];
    }
  } else {                   // grouped order: u1_0..u1_3,u2_0..u2_3,u3_0..u3_3
    for (int i = 0; i < 4; ++i) {
      u1s[i] = (const float*)d_in[2 + i];
      u2s[i] = (const float*)d_in[6 + i];
      u3s[i] = (const float*)d_in[10 + i];
    }
  }
  const float* w1   = (const float*)d_in[14];
  const float* w2   = (const float*)d_in[15];
  const float* w3   = (const float*)d_in[16];
  const float* wlin = (const float*)d_in[17];
  float* out = (float*)d_out;
  (void)d_ws; (void)ws_size; (void)out_size; (void)n_in;

  build_all<<<112, 256, 0, stream>>>(
      u1s[0], u1s[1], u1s[2], u1s[3],
      u2s[0], u2s[1], u2s[2], u2s[3],
      u3s[0], u3s[1], u3s[2], u3s[3], wlin);
  eqp_mm<<<N_NODES / 2, 1024, 0, stream>>>(x, specie, w1, w2, w3, out);
}

// Round 15
// 84.651 us; speedup vs baseline: 3.4811x; 3.4811x over previous
//
#include <hip/hip_runtime.h>

#define N_NODES 512
#define C_CH    128
#define S_SPEC  10
#define KT      50
#define NT      11

typedef _Float16 h8 __attribute__((ext_vector_type(8)));
typedef float f32x4 __attribute__((ext_vector_type(4)));

// K layout: 50 tiles x 32 slots; tile = 4 octets (one per lane-group g).
// Octet = (offA, offB, j0): slot i computes x[offA]*x[offB]*x[j0+i], j0 in {0,8}.
// N cols (o-major): nt 0..6 = k3, 7..9 = k2, 10 = k1; col = o (0..15).
// Fragment linearization: fi = kt*7+nt (kt<43); 301+(kt-43)*3+(nt-7); 319 (kt=49).
__device__ h8 g_Bf[KT * NT * 64];   // B pre-swizzled to MFMA B-frag order [kt][nt][lane]
__device__ h8 g_Wf[128 * 64];       // wlin as A-frags: [mt*16+ks][lane], K-expanded (ir,cc)

__device__ __forceinline__ void o_to_iri(int o, int& ir, int& i) {
  if (o >= 9)      { ir = 3; i = o - 9; }
  else if (o >= 4) { ir = 2; i = o - 4; }
  else if (o >= 1) { ir = 1; i = o - 1; }
  else             { ir = 0; i = 0; }
}

__device__ int octet_desc(int Q) {
  if (Q < 172) {                     // order-3
    int q = Q;
    for (int a = 0; a < 16; ++a)
      for (int b = a; b < 16; ++b) {
        int no = (b < 8) ? 2 : 1;
        if (q < no) {
          int jb = (no == 1) ? 1 : q;          // b<8: q0->j0=0,q1->j0=8; b>=8: j0=8
          return a | (b << 5) | (jb << 10);
        }
        q -= no;
      }
  } else if (Q < 196) {              // order-2
    int q = Q - 172;
    for (int a = 0; a < 16; ++a) {
      int no = (a < 8) ? 2 : 1;
      if (q < no) {
        int jb = (no == 1) ? 1 : q;
        return a | (16 << 5) | (jb << 10);
      }
      q -= no;
    }
  } else if (Q < 198) {              // order-1
    return 16 | (16 << 5) | ((Q - 196) << 10);
  }
  return 17 | (17 << 5);             // pad (zero column)
}

// ---- merged build: virtual bids 0..319 build B fragments, 320..447 build W fragments ----
__global__ void build_all(const float* __restrict__ u1_0, const float* __restrict__ u1_1,
                          const float* __restrict__ u1_2, const float* __restrict__ u1_3,
                          const float* __restrict__ u2_0, const float* __restrict__ u2_1,
                          const float* __restrict__ u2_2, const float* __restrict__ u2_3,
                          const float* __restrict__ u3_0, const float* __restrict__ u3_1,
                          const float* __restrict__ u3_2, const float* __restrict__ u3_3,
                          const float* __restrict__ wlin) {
  const int id  = blockIdx.x * 256 + threadIdx.x;   // 112*256 = 448*64
  const int bid = id >> 6;
  const int l   = id & 63;
  const int dis[4] = {1, 3, 5, 7};
  if (bid < 320) {
    int kt, nt;
    if (bid < 301)      { kt = bid / 7; nt = bid % 7; }
    else if (bid < 319) { int e = bid - 301; kt = 43 + e / 3; nt = 7 + e % 3; }
    else                { kt = 49; nt = 10; }

    const int o = l & 15;
    int ir, ii; o_to_iri(o, ir, ii);
    const int di = dis[ir];
    const float* u1s[4] = {u1_0, u1_1, u1_2, u1_3};
    const float* u2s[4] = {u2_0, u2_1, u2_2, u2_3};
    const float* u3s[4] = {u3_0, u3_1, u3_2, u3_3};

    const int rt = octet_desc(kt * 4 + (l >> 4));
    const int oA = rt & 31, oB = (rt >> 5) & 31, j0 = ((rt >> 10) & 1) * 8;

    h8 v;
#pragma unroll
    for (int i = 0; i < 8; ++i) {
      const int j = j0 + i;
      float val = 0.f;
      if (oA < 16 && oB < 16) {              // order-3, canonical a<=b<=j
        if (j >= oB) {
          const float* u = u3s[ir];
          int a = oA, b = oB;
          int P[6][3] = {{a,b,j},{a,j,b},{b,a,j},{b,j,a},{j,a,b},{j,b,a}};
          for (int p = 0; p < 6; ++p) {
            bool dup = false;
            for (int r = 0; r < p; ++r)
              if (P[r][0] == P[p][0] && P[r][1] == P[p][1] && P[r][2] == P[p][2]) { dup = true; break; }
            if (!dup)
              val += u[(((P[p][0] * 16 + P[p][1]) * 16 + P[p][2]) * 7 + nt) * di + ii];
          }
        }
      } else if (oA < 16 && oB == 16) {      // order-2 (oA <= j)
        if (j >= oA) {
          const int k2 = nt - 7;
          const float* u = u2s[ir];
          val = u[((oA * 16 + j) * 3 + k2) * di + ii];
          if (j != oA) val += u[((j * 16 + oA) * 3 + k2) * di + ii];
        }
      } else if (oA == 16) {                 // order-1
        val = u1s[ir][j * di + ii];
      }
      v[i] = (_Float16)val;
    }
    g_Bf[((size_t)kt * NT + nt) * 64 + l] = v;
  } else {
    // wlin -> fp16 A-frags over expanded K = (ir*128+cc), scaled by 1/sqrt(128)
    const int idW = (bid - 320) * 64 + l;    // 8192 total
    const int ks = (idW >> 6) & 15, mt = idW >> 10;
    const int f = mt * 16 + (l & 15);
    const float inv = 0.08838834764831845f;
    h8 v;
#pragma unroll
    for (int i = 0; i < 8; ++i) {
      const int k = ks * 32 + (l >> 4) * 8 + i;
      const int ir = k >> 7, cc = k & 127;
      v[i] = (_Float16)(wlin[((size_t)ir * C_CH + cc) * C_CH + f] * inv);
    }
    g_Wf[(mt * 16 + ks) * 64 + l] = v;
  }
}

// ---------------- fused main kernel: R10 + explicit register B-prefetch pipeline ----------------
// NOTE: no min-waves in __launch_bounds__ (R1/R4/R8/R13 spilled when capped). True per-wave
// register state ~180 (VGPR+AGPR unified) -> 2 waves/SIMD structural; 1 block/CU by LDS.

#define MFMA16(A, B, C) __builtin_amdgcn_mfma_f32_16x16x32_f16(A, B, C, 0, 0, 0)

__global__ __launch_bounds__(512, 1) void eqp_mm(
    const float* __restrict__ x, const int* __restrict__ specie,
    const float* __restrict__ w1, const float* __restrict__ w2,
    const float* __restrict__ w3, float* __restrict__ out) {
  __shared__ __align__(16) char bs[2][70 * 1024];   // B chunk double buffer (Ef aliases later)
  __shared__ float xT[2][128][18];                  // cols 0..15 x, 16 = 1, 17 = 0
  __shared__ int rtab[KT * 4];

  const int t = threadIdx.x;
  const int l = t & 63;
  const int w = t >> 6;
  const int g = l >> 4;
  const int n0 = blockIdx.x * 2;

  {  // stage xT + rtab
    const int p = t >> 8, c = (t >> 1) & 127, half = t & 1;
    const float* xp = x + ((size_t)(n0 + p) * C_CH + c) * 16 + half * 8;
    const float4 v0 = *(const float4*)xp, v1 = *(const float4*)(xp + 4);
    float* row = &xT[p][c][half * 8];
    row[0] = v0.x; row[1] = v0.y; row[2] = v0.z; row[3] = v0.w;
    row[4] = v1.x; row[5] = v1.y; row[6] = v1.z; row[7] = v1.w;
    if (half == 1) { xT[p][c][16] = 1.f; xT[p][c][17] = 0.f; }
    if (t < KT * 4) rtab[t] = octet_desc(t);
  }

  const int ch = w * 16 + (l & 15);
  const int s0 = specie[n0], s1 = specie[n0 + 1];

  // pre-convert this lane's channel rows to packed fp16 (RTE) for pk-mul production
  auto packh = [](float4 u, float4 v) {
    h8 r;
    r[0] = (_Float16)u.x; r[1] = (_Float16)u.y; r[2] = (_Float16)u.z; r[3] = (_Float16)u.w;
    r[4] = (_Float16)v.x; r[5] = (_Float16)v.y; r[6] = (_Float16)v.z; r[7] = (_Float16)v.w;
    return r;
  };
  h8 xh0l, xh0h, xh1l, xh1h;
  {
    const float4* p0 = (const float4*)(x + ((size_t)n0 * C_CH + ch) * 16);
    xh0l = packh(p0[0], p0[1]); xh0h = packh(p0[2], p0[3]);
    const float4* p1 = (const float4*)(x + ((size_t)(n0 + 1) * C_CH + ch) * 16);
    xh1l = packh(p1[0], p1[1]); xh1h = packh(p1[2], p1[3]);
  }

  f32x4 acc[2][NT];
#pragma unroll
  for (int p = 0; p < 2; ++p)
#pragma unroll
    for (int i = 0; i < NT; ++i) acc[p][i] = (f32x4){0.f, 0.f, 0.f, 0.f};

  h8 tv[9]; int dst[9];

  auto issue = [&](int ck) {
    const int f0 = ck * 70;
    const int nf = (ck < 4) ? 70 : 40;
#pragma unroll
    for (int slot = 0; slot < 9; ++slot) {
      const int r = slot * 8 + w;
      const bool ok = r < nf;
      const int fi = f0 + r;
      int kt, nt;
      if (fi < 301)      { kt = fi / 7;  nt = fi % 7; }
      else if (fi < 319) { kt = 43 + (fi - 301) / 3; nt = 7 + (fi - 301) % 3; }
      else               { kt = 49; nt = 10; }
      dst[slot] = ok ? r : -1;
      if (ok) tv[slot] = g_Bf[((size_t)kt * NT + nt) * 64 + l];
    }
  };
  auto wr = [&](char* buf) {
#pragma unroll
    for (int slot = 0; slot < 9; ++slot)
      if (dst[slot] >= 0) *(h8*)&buf[(size_t)dst[slot] * 1024 + (size_t)l * 16] = tv[slot];
  };

#define FR(tt, i) (*(const h8*)&buf[(size_t)((tt) * 7 + (i)) * 1024 + (size_t)l * 16])
#define BRD(i)    (*(const h8*)&buf[(size_t)(fb2 + (i)) * 1024 + (size_t)l * 16])

  // af generation for both nodes of tile kt
  auto afgen = [&](int kt, h8& af0, h8& af1) {
    const int rt_ = rtab[kt * 4 + g];
    const int oA_ = rt_ & 31, oB_ = (rt_ >> 5) & 31, jb_ = (rt_ >> 10) & 1;
    const float xab0 = xT[0][ch][oA_] * xT[0][ch][oB_];
    const float xab1 = xT[1][ch][oA_] * xT[1][ch][oB_];
    const _Float16 hm0 = (_Float16)xab0, hm1 = (_Float16)xab1;   // RTE
    const h8 m0 = {hm0, hm0, hm0, hm0, hm0, hm0, hm0, hm0};
    const h8 m1 = {hm1, hm1, hm1, hm1, hm1, hm1, hm1, hm1};
    af0 = m0 * (jb_ ? xh0h : xh0l);   // v_pk_mul_f16
    af1 = m1 * (jb_ ? xh1h : xh1l);
  };

  // chunks 0..3: 10 uniform 7-frag tiles, explicit 1-tile-deep register B prefetch
  auto consume7 = [&](int ck, const char* buf) {
    const int cs = ck * 10;
    h8 b0 = FR(0, 0), b1 = FR(0, 1), b2 = FR(0, 2), b3 = FR(0, 3),
       b4 = FR(0, 4), b5 = FR(0, 5), b6 = FR(0, 6);
#pragma unroll
    for (int tt = 0; tt < 10; ++tt) {
      h8 n0, n1, n2, n3, n4, n5, n6;
      if (tt < 9) {   // issue next tile's LDS loads before this tile's MFMAs
        n0 = FR(tt + 1, 0); n1 = FR(tt + 1, 1); n2 = FR(tt + 1, 2); n3 = FR(tt + 1, 3);
        n4 = FR(tt + 1, 4); n5 = FR(tt + 1, 5); n6 = FR(tt + 1, 6);
      }
      h8 af0, af1;
      afgen(cs + tt, af0, af1);
      acc[0][0] = MFMA16(af0, b0, acc[0][0]); acc[1][0] = MFMA16(af1, b0, acc[1][0]);
      acc[0][1] = MFMA16(af0, b1, acc[0][1]); acc[1][1] = MFMA16(af1, b1, acc[1][1]);
      acc[0][2] = MFMA16(af0, b2, acc[0][2]); acc[1][2] = MFMA16(af1, b2, acc[1][2]);
      acc[0][3] = MFMA16(af0, b3, acc[0][3]); acc[1][3] = MFMA16(af1, b3, acc[1][3]);
      acc[0][4] = MFMA16(af0, b4, acc[0][4]); acc[1][4] = MFMA16(af1, b4, acc[1][4]);
      acc[0][5] = MFMA16(af0, b5, acc[0][5]); acc[1][5] = MFMA16(af1, b5, acc[1][5]);
      acc[0][6] = MFMA16(af0, b6, acc[0][6]); acc[1][6] = MFMA16(af1, b6, acc[1][6]);
      if (tt < 9) { b0 = n0; b1 = n1; b2 = n2; b3 = n3; b4 = n4; b5 = n5; b6 = n6; }
    }
  };

  // tail chunk (tiles 40..49, mixed frag counts) — R10's proven path
  auto consume_tail = [&](const char* buf) {
    int fb2 = 0;
#pragma unroll
    for (int tt = 0; tt < 10; ++tt) {
      const int kt = 40 + tt;
      h8 af0, af1;
      afgen(kt, af0, af1);
      if (kt < 43) {
        h8 b0 = BRD(0), b1 = BRD(1), b2 = BRD(2), b3 = BRD(3), b4 = BRD(4), b5 = BRD(5), b6 = BRD(6);
        acc[0][0] = MFMA16(af0, b0, acc[0][0]); acc[1][0] = MFMA16(af1, b0, acc[1][0]);
        acc[0][1] = MFMA16(af0, b1, acc[0][1]); acc[1][1] = MFMA16(af1, b1, acc[1][1]);
        acc[0][2] = MFMA16(af0, b2, acc[0][2]); acc[1][2] = MFMA16(af1, b2, acc[1][2]);
        acc[0][3] = MFMA16(af0, b3, acc[0][3]); acc[1][3] = MFMA16(af1, b3, acc[1][3]);
        acc[0][4] = MFMA16(af0, b4, acc[0][4]); acc[1][4] = MFMA16(af1, b4, acc[1][4]);
        acc[0][5] = MFMA16(af0, b5, acc[0][5]); acc[1][5] = MFMA16(af1, b5, acc[1][5]);
        acc[0][6] = MFMA16(af0, b6, acc[0][6]); acc[1][6] = MFMA16(af1, b6, acc[1][6]);
        fb2 += 7;
      } else if (kt < 49) {
        h8 b0 = BRD(0), b1 = BRD(1), b2 = BRD(2);
        acc[0][7] = MFMA16(af0, b0, acc[0][7]); acc[1][7] = MFMA16(af1, b0, acc[1][7]);
        acc[0][8] = MFMA16(af0, b1, acc[0][8]); acc[1][8] = MFMA16(af1, b1, acc[1][8]);
        acc[0][9] = MFMA16(af0, b2, acc[0][9]); acc[1][9] = MFMA16(af1, b2, acc[1][9]);
        fb2 += 3;
      } else {
        h8 b0 = BRD(0);
        acc[0][10] = MFMA16(af0, b0, acc[0][10]); acc[1][10] = MFMA16(af1, b0, acc[1][10]);
        fb2 += 1;
      }
    }
  };

  // ---- pipelined main loop: 5 chunks of 10 tiles; 1 barrier/chunk ----
  issue(0);
  __syncthreads();           // xT/rtab visible
  wr(bs[0]);
  __syncthreads();
#pragma unroll 1
  for (int ck = 0; ck < 5; ++ck) {
    if (ck < 4) issue(ck + 1);
    if (ck < 4) consume7(ck, bs[ck & 1]);
    else        consume_tail(bs[ck & 1]);
    if (ck < 4) {
      wr(bs[(ck & 1) ^ 1]);   // that buffer was consumed a chunk ago, barrier-separated
      __syncthreads();
    }
  }
  __syncthreads();   // all B reads done; safe to alias bs as Ef

  // ---- species fold -> Ef (fp16, K-expanded (ir,cc)), zero-padded ----
  _Float16* Ef = (_Float16*)&bs[0][0];   // [p][ks(16)][lg(4)][o(16)][i(8)] = 32 KB
  {
    float4 z4 = {0.f, 0.f, 0.f, 0.f};
    float4* zp = (float4*)&bs[0][0];
    zp[t] = z4; zp[t + 512] = z4; zp[t + 1024] = z4; zp[t + 1536] = z4;
  }
  __syncthreads();
  {
    const int o = l & 15;
    int ir, ii; o_to_iri(o, ir, ii); (void)ii;
    const int cb = w * 16 + g * 4;
#pragma unroll
    for (int p = 0; p < 2; ++p) {
      const int sp = p ? s1 : s0;
      float tot[4] = {0.f, 0.f, 0.f, 0.f};
#pragma unroll
      for (int k = 0; k < 7; ++k) {
        const float4 wv = *(const float4*)(w3 + ((size_t)(ir * S_SPEC + sp) * 7 + k) * C_CH + cb);
        tot[0] = fmaf(wv.x, acc[p][k][0], tot[0]);
        tot[1] = fmaf(wv.y, acc[p][k][1], tot[1]);
        tot[2] = fmaf(wv.z, acc[p][k][2], tot[2]);
        tot[3] = fmaf(wv.w, acc[p][k][3], tot[3]);
      }
#pragma unroll
      for (int k = 0; k < 3; ++k) {
        const float4 wv = *(const float4*)(w2 + ((size_t)(ir * S_SPEC + sp) * 3 + k) * C_CH + cb);
        tot[0] = fmaf(wv.x, acc[p][7 + k][0], tot[0]);
        tot[1] = fmaf(wv.y, acc[p][7 + k][1], tot[1]);
        tot[2] = fmaf(wv.z, acc[p][7 + k][2], tot[2]);
        tot[3] = fmaf(wv.w, acc[p][7 + k][3], tot[3]);
      }
      {
        const float4 wv = *(const float4*)(w1 + (size_t)(ir * S_SPEC + sp) * C_CH + cb);
        tot[0] = fmaf(wv.x, acc[p][10][0], tot[0]);
        tot[1] = fmaf(wv.y, acc[p][10][1], tot[1]);
        tot[2] = fmaf(wv.z, acc[p][10][2], tot[2]);
        tot[3] = fmaf(wv.w, acc[p][10][3], tot[3]);
      }
#pragma unroll
      for (int r = 0; r < 4; ++r) {
        const int k = ir * 128 + cb + r;   // expanded K index
        Ef[((((size_t)p * 16 + (k >> 5)) * 4 + ((k >> 3) & 3)) * 16 + o) * 8 + (k & 7)] =
            (_Float16)tot[r];
      }
    }
  }
  __syncthreads();

  // ---- wlin channel mix via MFMA: D[f][o] = sum_k Wall[f][k] * Ef[k][o] ----
  {
    f32x4 D0 = {0.f, 0.f, 0.f, 0.f}, D1 = {0.f, 0.f, 0.f, 0.f};
#pragma unroll
    for (int ks = 0; ks < 16; ++ks) {
      const h8 aw = g_Wf[(w * 16 + ks) * 64 + l];
      const h8 b0 = *(const h8*)&Ef[(((size_t)0 * 16 + ks) * 4 + (l >> 4)) * 128 + (size_t)(l & 15) * 8];
      const h8 b1 = *(const h8*)&Ef[(((size_t)1 * 16 + ks) * 4 + (l >> 4)) * 128 + (size_t)(l & 15) * 8];
      D0 = MFMA16(aw, b0, D0);
      D1 = MFMA16(aw, b1, D1);
    }
    const int o = l & 15;
    int ir, ii; o_to_iri(o, ir, ii);
    const int dis[4]  = {1, 3, 5, 7};
    const int ooff[4] = {0, 128, 512, 1152};
#pragma unroll
    for (int p = 0; p < 2; ++p) {
      const f32x4 D = p ? D1 : D0;
      const size_t base = (size_t)(n0 + p) * 2048 + ooff[ir] + ii;
#pragma unroll
      for (int r = 0; r < 4; ++r) {
        const int f = w * 16 + (l >> 4) * 4 + r;
        out[base + (size_t)f * dis[ir]] = D[r];
      }
    }
  }
}

// ---------------- launch ----------------

extern "C" void kernel_launch(void* const* d_in, const int* in_sizes, int n_in,
                              void* d_out, int out_size, void* d_ws, size_t ws_size,
                              hipStream_t stream) {
  const float* x      = (const float*)d_in[0];
  const int*   specie = (const int*)d_in[1];

  const float *u1s[4], *u2s[4], *u3s[4];
  if (in_sizes[3] == 768) {  // interleaved dict order: u1_0,u2_0,u3_0,u1_1,...
    for (int i = 0; i < 4; ++i) {
      u1s[i] = (const float*)d_in[2 + 3 * i];
      u2s[i] = (const float*)d_in[3 + 3 * i];
      u3s[i] = (const float*)d_in[4 + 3 * i];
    }
  } else {                   // grouped order: u1_0..u1_3,u2_0..u2_3,u3_0..u3_3
    for (int i = 0; i < 4; ++i) {
      u1s[i] = (const float*)d_in[2 + i];
      u2s[i] = (const float*)d_in[6 + i];
      u3s[i] = (const float*)d_in[10 + i];
    }
  }
  const float* w1   = (const float*)d_in[14];
  const float* w2   = (const float*)d_in[15];
  const float* w3   = (const float*)d_in[16];
  const float* wlin = (const float*)d_in[17];
  float* out = (float*)d_out;
  (void)d_ws; (void)ws_size; (void)out_size; (void)n_in;

  build_all<<<112, 256, 0, stream>>>(
      u1s[0], u1s[1], u1s[2], u1s[3],
      u2s[0], u2s[1], u2s[2], u2s[3],
      u3s[0], u3s[1], u3s[2], u3s[3], wlin);
  eqp_mm<<<N_NODES / 2, 512, 0, stream>>>(x, specie, w1, w2, w3, out);
}

// Round 16
// 62.728 us; speedup vs baseline: 4.6977x; 1.3495x over previous
//
#include <hip/hip_runtime.h>

#define N_NODES 512
#define C_CH    128
#define S_SPEC  10
#define KT      50
#define NT      11

typedef _Float16 h8 __attribute__((ext_vector_type(8)));
typedef float f32x4 __attribute__((ext_vector_type(4)));

// K layout: 50 tiles x 32 slots; tile = 4 octets (one per lane-group g).
// Octet = (offA, offB, j0): slot i computes x[offA]*x[offB]*x[j0+i], j0 in {0,8}.
// N cols (o-major): nt 0..6 = k3, 7..9 = k2, 10 = k1; col = o (0..15).
// Fragment linearization: fi = kt*7+nt (kt<43); 301+(kt-43)*3+(nt-7); 319 (kt=49).
__device__ h8 g_Bf[KT * NT * 64];   // B pre-swizzled to MFMA B-frag order [kt][nt][lane]
__device__ h8 g_Wf[128 * 64];       // wlin as A-frags: [mt*16+ks][lane], K-expanded (ir,cc)

__device__ __forceinline__ void o_to_iri(int o, int& ir, int& i) {
  if (o >= 9)      { ir = 3; i = o - 9; }
  else if (o >= 4) { ir = 2; i = o - 4; }
  else if (o >= 1) { ir = 1; i = o - 1; }
  else             { ir = 0; i = 0; }
}

__device__ int octet_desc(int Q) {
  if (Q < 172) {                     // order-3
    int q = Q;
    for (int a = 0; a < 16; ++a)
      for (int b = a; b < 16; ++b) {
        int no = (b < 8) ? 2 : 1;
        if (q < no) {
          int jb = (no == 1) ? 1 : q;          // b<8: q0->j0=0,q1->j0=8; b>=8: j0=8
          return a | (b << 5) | (jb << 10);
        }
        q -= no;
      }
  } else if (Q < 196) {              // order-2
    int q = Q - 172;
    for (int a = 0; a < 16; ++a) {
      int no = (a < 8) ? 2 : 1;
      if (q < no) {
        int jb = (no == 1) ? 1 : q;
        return a | (16 << 5) | (jb << 10);
      }
      q -= no;
    }
  } else if (Q < 198) {              // order-1
    return 16 | (16 << 5) | ((Q - 196) << 10);
  }
  return 17 | (17 << 5);             // pad (zero column)
}

// ---- merged build: virtual bids 0..319 build B fragments, 320..447 build W fragments ----
__global__ void build_all(const float* __restrict__ u1_0, const float* __restrict__ u1_1,
                          const float* __restrict__ u1_2, const float* __restrict__ u1_3,
                          const float* __restrict__ u2_0, const float* __restrict__ u2_1,
                          const float* __restrict__ u2_2, const float* __restrict__ u2_3,
                          const float* __restrict__ u3_0, const float* __restrict__ u3_1,
                          const float* __restrict__ u3_2, const float* __restrict__ u3_3,
                          const float* __restrict__ wlin) {
  const int id  = blockIdx.x * 256 + threadIdx.x;   // 112*256 = 448*64
  const int bid = id >> 6;
  const int l   = id & 63;
  const int dis[4] = {1, 3, 5, 7};
  if (bid < 320) {
    int kt, nt;
    if (bid < 301)      { kt = bid / 7; nt = bid % 7; }
    else if (bid < 319) { int e = bid - 301; kt = 43 + e / 3; nt = 7 + e % 3; }
    else                { kt = 49; nt = 10; }

    const int o = l & 15;
    int ir, ii; o_to_iri(o, ir, ii);
    const int di = dis[ir];
    const float* u1s[4] = {u1_0, u1_1, u1_2, u1_3};
    const float* u2s[4] = {u2_0, u2_1, u2_2, u2_3};
    const float* u3s[4] = {u3_0, u3_1, u3_2, u3_3};

    const int rt = octet_desc(kt * 4 + (l >> 4));
    const int oA = rt & 31, oB = (rt >> 5) & 31, j0 = ((rt >> 10) & 1) * 8;

    h8 v;
#pragma unroll
    for (int i = 0; i < 8; ++i) {
      const int j = j0 + i;
      float val = 0.f;
      if (oA < 16 && oB < 16) {              // order-3, canonical a<=b<=j
        if (j >= oB) {
          const float* u = u3s[ir];
          int a = oA, b = oB;
          int P[6][3] = {{a,b,j},{a,j,b},{b,a,j},{b,j,a},{j,a,b},{j,b,a}};
          for (int p = 0; p < 6; ++p) {
            bool dup = false;
            for (int r = 0; r < p; ++r)
              if (P[r][0] == P[p][0] && P[r][1] == P[p][1] && P[r][2] == P[p][2]) { dup = true; break; }
            if (!dup)
              val += u[(((P[p][0] * 16 + P[p][1]) * 16 + P[p][2]) * 7 + nt) * di + ii];
          }
        }
      } else if (oA < 16 && oB == 16) {      // order-2 (oA <= j)
        if (j >= oA) {
          const int k2 = nt - 7;
          const float* u = u2s[ir];
          val = u[((oA * 16 + j) * 3 + k2) * di + ii];
          if (j != oA) val += u[((j * 16 + oA) * 3 + k2) * di + ii];
        }
      } else if (oA == 16) {                 // order-1
        val = u1s[ir][j * di + ii];
      }
      v[i] = (_Float16)val;
    }
    g_Bf[((size_t)kt * NT + nt) * 64 + l] = v;
  } else {
    // wlin -> fp16 A-frags over expanded K = (ir*128+cc), scaled by 1/sqrt(128)
    const int idW = (bid - 320) * 64 + l;    // 8192 total
    const int ks = (idW >> 6) & 15, mt = idW >> 10;
    const int f = mt * 16 + (l & 15);
    const float inv = 0.08838834764831845f;
    h8 v;
#pragma unroll
    for (int i = 0; i < 8; ++i) {
      const int k = ks * 32 + (l >> 4) * 8 + i;
      const int ir = k >> 7, cc = k & 127;
      v[i] = (_Float16)(wlin[((size_t)ir * C_CH + cc) * C_CH + f] * inv);
    }
    g_Wf[(mt * 16 + ks) * 64 + l] = v;
  }
}

// ---------------- fused main kernel: 2 nodes/block, 10-tile chunks, pk-mul production ----
// NOTE: no min-waves in __launch_bounds__ (R1/R4/R8/R13/R14 spilled when the allocator was
// capped below live-register demand, incl. its own 128-cap heuristic when extra regs are
// requested). True per-wave state ~180 regs (VGPR+AGPR unified) -> 2 waves/SIMD structural;
// 1 block/CU by LDS. This is the measured-best configuration (R10: 62.5 us total).

#define MFMA16(A, B, C) __builtin_amdgcn_mfma_f32_16x16x32_f16(A, B, C, 0, 0, 0)

__global__ __launch_bounds__(512, 1) void eqp_mm(
    const float* __restrict__ x, const int* __restrict__ specie,
    const float* __restrict__ w1, const float* __restrict__ w2,
    const float* __restrict__ w3, float* __restrict__ out) {
  __shared__ __align__(16) char bs[2][70 * 1024];   // B chunk double buffer (Ef aliases later)
  __shared__ float xT[2][128][18];                  // cols 0..15 x, 16 = 1, 17 = 0
  __shared__ int rtab[KT * 4];

  const int t = threadIdx.x;
  const int l = t & 63;
  const int w = t >> 6;
  const int g = l >> 4;
  const int n0 = blockIdx.x * 2;

  {  // stage xT + rtab
    const int p = t >> 8, c = (t >> 1) & 127, half = t & 1;
    const float* xp = x + ((size_t)(n0 + p) * C_CH + c) * 16 + half * 8;
    const float4 v0 = *(const float4*)xp, v1 = *(const float4*)(xp + 4);
    float* row = &xT[p][c][half * 8];
    row[0] = v0.x; row[1] = v0.y; row[2] = v0.z; row[3] = v0.w;
    row[4] = v1.x; row[5] = v1.y; row[6] = v1.z; row[7] = v1.w;
    if (half == 1) { xT[p][c][16] = 1.f; xT[p][c][17] = 0.f; }
    if (t < KT * 4) rtab[t] = octet_desc(t);
  }

  const int ch = w * 16 + (l & 15);
  const int s0 = specie[n0], s1 = specie[n0 + 1];

  // pre-convert this lane's channel rows to packed fp16 (RTE) for pk-mul production
  auto packh = [](float4 u, float4 v) {
    h8 r;
    r[0] = (_Float16)u.x; r[1] = (_Float16)u.y; r[2] = (_Float16)u.z; r[3] = (_Float16)u.w;
    r[4] = (_Float16)v.x; r[5] = (_Float16)v.y; r[6] = (_Float16)v.z; r[7] = (_Float16)v.w;
    return r;
  };
  h8 xh0l, xh0h, xh1l, xh1h;
  {
    const float4* p0 = (const float4*)(x + ((size_t)n0 * C_CH + ch) * 16);
    xh0l = packh(p0[0], p0[1]); xh0h = packh(p0[2], p0[3]);
    const float4* p1 = (const float4*)(x + ((size_t)(n0 + 1) * C_CH + ch) * 16);
    xh1l = packh(p1[0], p1[1]); xh1h = packh(p1[2], p1[3]);
  }

  f32x4 acc[2][NT];
#pragma unroll
  for (int p = 0; p < 2; ++p)
#pragma unroll
    for (int i = 0; i < NT; ++i) acc[p][i] = (f32x4){0.f, 0.f, 0.f, 0.f};

  h8 tv[9]; int dst[9];

  auto issue = [&](int ck) {
    const int f0 = ck * 70;
    const int nf = (ck < 4) ? 70 : 40;
#pragma unroll
    for (int slot = 0; slot < 9; ++slot) {
      const int r = slot * 8 + w;
      const bool ok = r < nf;
      const int fi = f0 + r;
      int kt, nt;
      if (fi < 301)      { kt = fi / 7;  nt = fi % 7; }
      else if (fi < 319) { kt = 43 + (fi - 301) / 3; nt = 7 + (fi - 301) % 3; }
      else               { kt = 49; nt = 10; }
      dst[slot] = ok ? r : -1;
      if (ok) tv[slot] = g_Bf[((size_t)kt * NT + nt) * 64 + l];
    }
  };
  auto wr = [&](char* buf) {
#pragma unroll
    for (int slot = 0; slot < 9; ++slot)
      if (dst[slot] >= 0) *(h8*)&buf[(size_t)dst[slot] * 1024 + (size_t)l * 16] = tv[slot];
  };

#define BRD(i) (*(const h8*)&buf[(size_t)(fb2 + (i)) * 1024 + (size_t)l * 16])

  auto consume = [&](int ck, const char* buf) {
    const int cs = ck * 10;
    int fb2 = 0;
#pragma unroll
    for (int tt = 0; tt < 10; ++tt) {
      const int kt = cs + tt;
      const int rt_ = rtab[kt * 4 + g];
      const int oA_ = rt_ & 31, oB_ = (rt_ >> 5) & 31, jb_ = (rt_ >> 10) & 1;
      const float xab0 = xT[0][ch][oA_] * xT[0][ch][oB_];
      const float xab1 = xT[1][ch][oA_] * xT[1][ch][oB_];
      const _Float16 hm0 = (_Float16)xab0, hm1 = (_Float16)xab1;   // RTE
      const h8 m0 = {hm0, hm0, hm0, hm0, hm0, hm0, hm0, hm0};
      const h8 m1 = {hm1, hm1, hm1, hm1, hm1, hm1, hm1, hm1};
      const h8 af0 = m0 * (jb_ ? xh0h : xh0l);   // 4x v_pk_mul_f16
      const h8 af1 = m1 * (jb_ ? xh1h : xh1l);
      if (kt < 43) {
        h8 b0 = BRD(0), b1 = BRD(1), b2 = BRD(2), b3 = BRD(3), b4 = BRD(4), b5 = BRD(5), b6 = BRD(6);
        acc[0][0] = MFMA16(af0, b0, acc[0][0]); acc[1][0] = MFMA16(af1, b0, acc[1][0]);
        acc[0][1] = MFMA16(af0, b1, acc[0][1]); acc[1][1] = MFMA16(af1, b1, acc[1][1]);
        acc[0][2] = MFMA16(af0, b2, acc[0][2]); acc[1][2] = MFMA16(af1, b2, acc[1][2]);
        acc[0][3] = MFMA16(af0, b3, acc[0][3]); acc[1][3] = MFMA16(af1, b3, acc[1][3]);
        acc[0][4] = MFMA16(af0, b4, acc[0][4]); acc[1][4] = MFMA16(af1, b4, acc[1][4]);
        acc[0][5] = MFMA16(af0, b5, acc[0][5]); acc[1][5] = MFMA16(af1, b5, acc[1][5]);
        acc[0][6] = MFMA16(af0, b6, acc[0][6]); acc[1][6] = MFMA16(af1, b6, acc[1][6]);
        fb2 += 7;
      } else if (kt < 49) {
        h8 b0 = BRD(0), b1 = BRD(1), b2 = BRD(2);
        acc[0][7] = MFMA16(af0, b0, acc[0][7]); acc[1][7] = MFMA16(af1, b0, acc[1][7]);
        acc[0][8] = MFMA16(af0, b1, acc[0][8]); acc[1][8] = MFMA16(af1, b1, acc[1][8]);
        acc[0][9] = MFMA16(af0, b2, acc[0][9]); acc[1][9] = MFMA16(af1, b2, acc[1][9]);
        fb2 += 3;
      } else {
        h8 b0 = BRD(0);
        acc[0][10] = MFMA16(af0, b0, acc[0][10]); acc[1][10] = MFMA16(af1, b0, acc[1][10]);
        fb2 += 1;
      }
    }
  };

  // ---- pipelined main loop: 5 chunks of 10 tiles; 1 barrier/chunk ----
  issue(0);
  __syncthreads();           // xT/rtab visible
  wr(bs[0]);
  __syncthreads();
#pragma unroll 1
  for (int ck = 0; ck < 5; ++ck) {
    if (ck < 4) issue(ck + 1);
    consume(ck, bs[ck & 1]);
    if (ck < 4) {
      wr(bs[(ck & 1) ^ 1]);   // that buffer was consumed a chunk ago, barrier-separated
      __syncthreads();
    }
  }
  __syncthreads();   // all B reads done; safe to alias bs as Ef

  // ---- species fold -> Ef (fp16, K-expanded (ir,cc)), zero-padded ----
  _Float16* Ef = (_Float16*)&bs[0][0];   // [p][ks(16)][lg(4)][o(16)][i(8)] = 32 KB
  {
    float4 z4 = {0.f, 0.f, 0.f, 0.f};
    float4* zp = (float4*)&bs[0][0];
    zp[t] = z4; zp[t + 512] = z4; zp[t + 1024] = z4; zp[t + 1536] = z4;
  }
  __syncthreads();
  {
    const int o = l & 15;
    int ir, ii; o_to_iri(o, ir, ii); (void)ii;
    const int cb = w * 16 + g * 4;
#pragma unroll
    for (int p = 0; p < 2; ++p) {
      const int sp = p ? s1 : s0;
      float tot[4] = {0.f, 0.f, 0.f, 0.f};
#pragma unroll
      for (int k = 0; k < 7; ++k) {
        const float4 wv = *(const float4*)(w3 + ((size_t)(ir * S_SPEC + sp) * 7 + k) * C_CH + cb);
        tot[0] = fmaf(wv.x, acc[p][k][0], tot[0]);
        tot[1] = fmaf(wv.y, acc[p][k][1], tot[1]);
        tot[2] = fmaf(wv.z, acc[p][k][2], tot[2]);
        tot[3] = fmaf(wv.w, acc[p][k][3], tot[3]);
      }
#pragma unroll
      for (int k = 0; k < 3; ++k) {
        const float4 wv = *(const float4*)(w2 + ((size_t)(ir * S_SPEC + sp) * 3 + k) * C_CH + cb);
        tot[0] = fmaf(wv.x, acc[p][7 + k][0], tot[0]);
        tot[1] = fmaf(wv.y, acc[p][7 + k][1], tot[1]);
        tot[2] = fmaf(wv.z, acc[p][7 + k][2], tot[2]);
        tot[3] = fmaf(wv.w, acc[p][7 + k][3], tot[3]);
      }
      {
        const float4 wv = *(const float4*)(w1 + (size_t)(ir * S_SPEC + sp) * C_CH + cb);
        tot[0] = fmaf(wv.x, acc[p][10][0], tot[0]);
        tot[1] = fmaf(wv.y, acc[p][10][1], tot[1]);
        tot[2] = fmaf(wv.z, acc[p][10][2], tot[2]);
        tot[3] = fmaf(wv.w, acc[p][10][3], tot[3]);
      }
#pragma unroll
      for (int r = 0; r < 4; ++r) {
        const int k = ir * 128 + cb + r;   // expanded K index
        Ef[((((size_t)p * 16 + (k >> 5)) * 4 + ((k >> 3) & 3)) * 16 + o) * 8 + (k & 7)] =
            (_Float16)tot[r];
      }
    }
  }
  __syncthreads();

  // ---- wlin channel mix via MFMA: D[f][o] = sum_k Wall[f][k] * Ef[k][o] ----
  {
    f32x4 D0 = {0.f, 0.f, 0.f, 0.f}, D1 = {0.f, 0.f, 0.f, 0.f};
#pragma unroll
    for (int ks = 0; ks < 16; ++ks) {
      const h8 aw = g_Wf[(w * 16 + ks) * 64 + l];
      const h8 b0 = *(const h8*)&Ef[(((size_t)0 * 16 + ks) * 4 + (l >> 4)) * 128 + (size_t)(l & 15) * 8];
      const h8 b1 = *(const h8*)&Ef[(((size_t)1 * 16 + ks) * 4 + (l >> 4)) * 128 + (size_t)(l & 15) * 8];
      D0 = MFMA16(aw, b0, D0);
      D1 = MFMA16(aw, b1, D1);
    }
    const int o = l & 15;
    int ir, ii; o_to_iri(o, ir, ii);
    const int dis[4]  = {1, 3, 5, 7};
    const int ooff[4] = {0, 128, 512, 1152};
#pragma unroll
    for (int p = 0; p < 2; ++p) {
      const f32x4 D = p ? D1 : D0;
      const size_t base = (size_t)(n0 + p) * 2048 + ooff[ir] + ii;
#pragma unroll
      for (int r = 0; r < 4; ++r) {
        const int f = w * 16 + (l >> 4) * 4 + r;
        out[base + (size_t)f * dis[ir]] = D[r];
      }
    }
  }
}

// ---------------- launch ----------------

extern "C" void kernel_launch(void* const* d_in, const int* in_sizes, int n_in,
                              void* d_out, int out_size, void* d_ws, size_t ws_size,
                              hipStream_t stream) {
  const float* x      = (const float*)d_in[0];
  const int*   specie = (const int*)d_in[1];

  const float *u1s[4], *u2s[4], *u3s[4];
  if (in_sizes[3] == 768) {  // interleaved dict order: u1_0,u2_0,u3_0,u1_1,...
    for (int i = 0; i < 4; ++i) {
      u1s[i] = (const float*)d_in[2 + 3 * i];
      u2s[i] = (const float*)d_in[3 + 3 * i];
      u3s[i] = (const float*)d_in[4 + 3 * i];
    }
  } else {                   // grouped order: u1_0..u1_3,u2_0..u2_3,u3_0..u3_3
    for (int i = 0; i < 4; ++i) {
      u1s[i] = (const float*)d_in[2 + i];
      u2s[i] = (const float*)d_in[6 + i];
      u3s[i] = (const float*)d_in[10 + i];
    }
  }
  const float* w1   = (const float*)d_in[14];
  const float* w2   = (const float*)d_in[15];
  const float* w3   = (const float*)d_in[16];
  const float* wlin = (const float*)d_in[17];
  float* out = (float*)d_out;
  (void)d_ws; (void)ws_size; (void)out_size; (void)n_in;

  build_all<<<112, 256, 0, stream>>>(
      u1s[0], u1s[1], u1s[2], u1s[3],
      u2s[0], u2s[1], u2s[2], u2s[3],
      u3s[0], u3s[1], u3s[2], u3s[3], wlin);
  eqp_mm<<<N_NODES / 2, 512, 0, stream>>>(x, specie, w1, w2, w3, out);
}